// Round 7
// baseline (13299.393 us; speedup 1.0000x reference)
//
#include <hip/hip_runtime.h>
#include <hip/hip_fp16.h>

// AlternatingForecastModel: 4096-step LSTM (B=256,H=256) with anomaly memory blend.
// v7: stop fighting the allocator -- design to the 128-VGPR cap.
//   Evidence r4-r6: 512-thr blocks always get VGPR=128 (launch_bounds 2nd arg
//   ignored) -> 184 weight regs/thread spilled ~130 regs -> 99MB scratch, 10.9ms.
//   Fix: 1024 threads/block. W_hh f16 = 256KB: 144KB in LDS (proven layout) +
//   112KB in VGPRs = 92 regs/thread at 1024 thr -> fits under 128. 1024-thr
//   blocks force 4 waves/SIMD = exactly the compiler's preferred occupancy.
//   - thread = (unit u = tid>>2, slice s = tid&3); 4 gate-rows; acc[4]
//   - 23 W_hh pairs/row in VGPR (92), 9 pairs/row in LDS (144KB, [slot][tid][4dw])
//   - bias/W_out/b_out in LDS (read post-butterfly, broadcast, conflict-free)
//   - W=10 ring packed f16 (5 regs, alignbit shift) + packed softmax table
//   - butterfly via __shfl_xor over the 4 slices (proven)

#define Bb 256
#define Tt 4096
#define Ff 16
#define Hh 256
#define PV 23                    // W_hh pairs/row in VGPRs (pairs 0..22)
#define NSL 9                    // W_hh pairs/row in LDS  (pairs 23..31)
#define MEM_DECAY 0.3f
#define SMOOTH 0.1f

typedef _Float16 h2v __attribute__((ext_vector_type(2)));

__device__ __forceinline__ uint32_t pkh2(float a, float b) {
    __half2 h = __floats2half2_rn(a, b);
    return __builtin_bit_cast(uint32_t, h);
}

__device__ __forceinline__ float dot2f(uint32_t a, uint32_t b, float c) {
#if __has_builtin(__builtin_amdgcn_fdot2)
    return __builtin_amdgcn_fdot2(__builtin_bit_cast(h2v, a),
                                  __builtin_bit_cast(h2v, b), c, false);
#else
    h2v x = __builtin_bit_cast(h2v, a), y = __builtin_bit_cast(h2v, b);
    return c + (float)x[0] * (float)y[0] + (float)x[1] * (float)y[1];
#endif
}

__device__ __forceinline__ float sigm_(float x) { return 1.0f / (1.0f + __expf(-x)); }
__device__ __forceinline__ float tanh_(float x) { return 1.0f - 2.0f / (__expf(2.0f * x) + 1.0f); }

// ---------------- pre-kernel: packed anomaly bits (128 u32 words) ----------------
__global__ void __launch_bounds__(256) anom_kernel(const float* __restrict__ x,
                                                   uint32_t* __restrict__ anomw) {
    __shared__ uint32_t part[4][64];
    const int k = blockIdx.x, j = threadIdx.x;
    const int tsub = j & 63, bg = j >> 6;
    const int t = k * 64 + tsub;
    uint32_t a = 0;
    for (int b = bg * 64; b < bg * 64 + 64; ++b)
        a |= (x[((size_t)b * Tt + t) * Ff + (Ff - 1)] != 0.0f) ? 1u : 0u;
    part[bg][tsub] = a;
    __syncthreads();
    if (j < 64) {
        uint32_t any = part[0][j] | part[1][j] | part[2][j] | part[3][j];
        unsigned long long m = __ballot(any != 0);
        if (j == 0) {
            anomw[2 * k]     = (uint32_t)(m & 0xffffffffull);
            anomw[2 * k + 1] = (uint32_t)(m >> 32);
        }
    }
}

// ---------------- main kernel ----------------
__global__ void __launch_bounds__(1024) lstm_kernel(
    const float* __restrict__ x,
    const float* __restrict__ W_ih, const float* __restrict__ b_ih,
    const float* __restrict__ W_hh, const float* __restrict__ b_hh,
    const float* __restrict__ W_out, const float* __restrict__ b_out,
    const uint32_t* __restrict__ anomw,
    float* __restrict__ out)
{
    __shared__ uint4    lds_w4[NSL * 1024];           // 147456 B
    __shared__ float    bias_l[1024];                 // 4096 B  bias[u*4+G]
    __shared__ float    wout_l[256];                  // 1024 B
    __shared__ uint32_t xst[64 * 8];                  // 2048 B
    __shared__ uint32_t hbuf[2 * 144];                // 1152 B (h f16 pairs, stride 36/slice)
    __shared__ uint32_t abits[128];                   // 512 B
    __shared__ uint32_t w2h[64];                      // packed f16 softmax table
    __shared__ float    outp[2][16];                  // per-wave partials
    __shared__ float    bo_l;

    const int tid = threadIdx.x;          // 0..1023
    const int b   = blockIdx.x;
    const int s   = tid & 3;              // k-slice (h-cols [64s, 64s+64))
    const int u   = tid >> 2;             // unit 0..255

    // ---- VGPR W_hh: wv[G][k] = pair (cols 64s+2k, +1) of row G*256+u
    uint32_t wv[4][PV];
#pragma unroll
    for (int G = 0; G < 4; ++G) {
        const float* src = W_hh + (size_t)((G << 8) + u) * Hh + 64 * s;
#pragma unroll
        for (int k = 0; k < PV; ++k) {
            const float2 w2v = *reinterpret_cast<const float2*>(src + 2 * k);
            wv[G][k] = pkh2(w2v.x, w2v.y);
        }
    }
    // ---- VGPR W_ih: slice s owns features 4s..4s+3 (2 pairs/row)
    uint32_t wx[4][2];
#pragma unroll
    for (int G = 0; G < 4; ++G) {
        const float* src = W_ih + (size_t)((G << 8) + u) * (Ff + 1) + 4 * s;
        wx[G][0] = pkh2(src[0], src[1]);
        wx[G][1] = pkh2(src[2], src[3]);
    }

    // ---- LDS W_hh pairs PV..PV+NSL-1: slot j, [j][tid] = {pair j+PV of row G*256+u : G}
#pragma unroll 1
    for (int j = 0; j < NSL; ++j) {
        const int col = 64 * s + 2 * (PV + j);
        uint32_t d[4];
#pragma unroll
        for (int G = 0; G < 4; ++G) {
            const float2 w2v = *reinterpret_cast<const float2*>(
                W_hh + (size_t)((G << 8) + u) * Hh + col);
            d[G] = pkh2(w2v.x, w2v.y);
        }
        lds_w4[j * 1024 + tid] = make_uint4(d[0], d[1], d[2], d[3]);
    }

    // ---- misc LDS init
    bias_l[tid] = b_ih[((tid & 3) << 8) + (tid >> 2)] + b_hh[((tid & 3) << 8) + (tid >> 2)];
    if (tid < 256) wout_l[tid] = W_out[tid];
    if (tid == 0) bo_l = b_out[0];
    if (tid < 128) abits[tid] = anomw[tid];
    if (tid < 288) hbuf[tid] = 0u;                    // h0 = 0 (both phases)
    if (tid < 50) {
        const int cc = tid / 5 + 1, j = tid % 5;
        float S = 0.f;
        for (int i = 0; i < cc; ++i) S += __expf((float)i);
        const int shift = 10 - cc;
        const int p0 = 2 * j, p1 = 2 * j + 1;
        const float v0 = (p0 >= shift) ? __expf((float)(p0 - shift)) / S : 0.f;
        const float v1 = (p1 >= shift) ? __expf((float)(p1 - shift)) / S : 0.f;
        w2h[cc * 5 + j] = pkh2(v0, v1);
    }

    float c_reg = 0.f, h_last = 0.f;
    uint32_t bufp[5];                     // W=10 ring, packed f16, oldest = low of bufp[0]
#pragma unroll
    for (int i = 0; i < 5; ++i) bufp[i] = 0u;
    int count = 1;

    __syncthreads();

    unsigned short* hs = reinterpret_cast<unsigned short*>(hbuf);

#pragma unroll 1
    for (int tc = 0; tc < Tt / 64; ++tc) {
        if (tid < 512) {   // stage 64 steps of x as f16 pairs (waves 0-7)
            const int ts = tc * 64 + (tid >> 3), q = tid & 7;
            const float2 xv = *reinterpret_cast<const float2*>(
                &x[((size_t)b * Tt + ts) * Ff + 2 * q]);
            xst[(tid >> 3) * 8 + q] = pkh2(xv.x, xv.y);
        }
        __syncthreads();

#pragma unroll 1
        for (int tt = 0; tt < 64; ++tt) {
            const int t = tc * 64 + tt;
            const uint32_t* hb = hbuf + (t & 1) * 144 + s * 36;

            float acc[4];
#pragma unroll
            for (int G = 0; G < 4; ++G) acc[G] = 0.f;

            // ---- phase A: h pairs 23..31 + LDS weight slots
            {
                const uint32_t hA0 = hb[23];
                const uint4 hA1 = *reinterpret_cast<const uint4*>(hb + 24);
                const uint4 hA2 = *reinterpret_cast<const uint4*>(hb + 28);
                const uint32_t hkA[9] = {hA0, hA1.x, hA1.y, hA1.z, hA1.w,
                                              hA2.x, hA2.y, hA2.z, hA2.w};
#pragma unroll
                for (int j = 0; j < NSL; ++j) {
                    const uint32_t hk = hkA[j];
                    const uint4 wc = lds_w4[j * 1024 + tid];
                    acc[0] = dot2f(wc.x, hk, acc[0]);
                    acc[1] = dot2f(wc.y, hk, acc[1]);
                    acc[2] = dot2f(wc.z, hk, acc[2]);
                    acc[3] = dot2f(wc.w, hk, acc[3]);
                }
            }
            // ---- x part
            {
                const uint32_t xp0 = xst[tt * 8 + 2 * s];
                const uint32_t xp1 = xst[tt * 8 + 2 * s + 1];
#pragma unroll
                for (int G = 0; G < 4; ++G) {
                    acc[G] = dot2f(wx[G][0], xp0, acc[G]);
                    acc[G] = dot2f(wx[G][1], xp1, acc[G]);
                }
            }
            __builtin_amdgcn_sched_barrier(0);
            // ---- phase B1: h pairs 0..11
            {
                const uint4 h0 = *reinterpret_cast<const uint4*>(hb + 0);
                const uint4 h1 = *reinterpret_cast<const uint4*>(hb + 4);
                const uint4 h2 = *reinterpret_cast<const uint4*>(hb + 8);
                const uint32_t hkB[12] = {h0.x, h0.y, h0.z, h0.w,
                                          h1.x, h1.y, h1.z, h1.w,
                                          h2.x, h2.y, h2.z, h2.w};
#pragma unroll
                for (int k = 0; k < 12; ++k) {
                    const uint32_t hk = hkB[k];
#pragma unroll
                    for (int G = 0; G < 4; ++G)
                        acc[G] = dot2f(wv[G][k], hk, acc[G]);
                }
            }
            __builtin_amdgcn_sched_barrier(0);
            // ---- phase B2: h pairs 12..22
            {
                const uint4 h3 = *reinterpret_cast<const uint4*>(hb + 12);
                const uint4 h4 = *reinterpret_cast<const uint4*>(hb + 16);
                const uint32_t h20 = hb[20], h21 = hb[21], h22 = hb[22];
                const uint32_t hkC[11] = {h3.x, h3.y, h3.z, h3.w,
                                          h4.x, h4.y, h4.z, h4.w,
                                          h20, h21, h22};
#pragma unroll
                for (int k = 0; k < 11; ++k) {
                    const uint32_t hk = hkC[k];
#pragma unroll
                    for (int G = 0; G < 4; ++G)
                        acc[G] = dot2f(wv[G][12 + k], hk, acc[G]);
                }
            }

            // butterfly across the 4 k-slices
#pragma unroll
            for (int G = 0; G < 4; ++G) acc[G] += __shfl_xor(acc[G], 1, 64);
#pragma unroll
            for (int G = 0; G < 4; ++G) acc[G] += __shfl_xor(acc[G], 2, 64);

            // bias from LDS (quad-broadcast b128, conflict-free)
            const float4 bi = *reinterpret_cast<const float4*>(&bias_l[u * 4]);
            const float ig = sigm_(acc[0] + bi.x);
            const float fg = sigm_(acc[1] + bi.y);
            const float gg = tanh_(acc[2] + bi.z);
            const float og = sigm_(acc[3] + bi.w);
            const float new_c = fg * c_reg + ig * gg;
            const float new_h = og * tanh_(new_c);

            const uint32_t an = (abits[t >> 5] >> (t & 31)) & 1u;
            if (an) {
                const uint32_t* wt = w2h + count * 5;   // uniform addr -> broadcast
                float wsum = 0.f;
#pragma unroll
                for (int j = 0; j < 5; ++j) wsum = dot2f(wt[j], bufp[j], wsum);
                const float blend = wsum * (1.0f - MEM_DECAY) + new_c * MEM_DECAY;
                c_reg = c_reg * (1.0f - SMOOTH) + blend * SMOOTH;
            } else {
                c_reg = new_c;
                __half nch = __float2half_rn(new_c);
                const uint32_t nc = (uint32_t)__builtin_bit_cast(unsigned short, nch);
                bufp[0] = __builtin_amdgcn_alignbit(bufp[1], bufp[0], 16);
                bufp[1] = __builtin_amdgcn_alignbit(bufp[2], bufp[1], 16);
                bufp[2] = __builtin_amdgcn_alignbit(bufp[3], bufp[2], 16);
                bufp[3] = __builtin_amdgcn_alignbit(bufp[4], bufp[3], 16);
                bufp[4] = __builtin_amdgcn_alignbit(nc,      bufp[4], 16);
                count = min(count + 1, 10);
            }
            h_last = new_h;

            // publish h (f16) for step t+1, padded layout (one lane per unit)
            if (s == 0) {
                __half hv = __float2half_rn(new_h);
                hs[((t + 1) & 1) * 288 + (u >> 6) * 72 + (u & 63)] =
                    __builtin_bit_cast(unsigned short, hv);
            }
            // out[b][t]: per-wave shfl reduce (each unit counted once via s==0)
            float ov = (s == 0) ? new_h * wout_l[u] : 0.f;
#pragma unroll
            for (int m = 1; m < 64; m <<= 1) ov += __shfl_xor(ov, m, 64);
            if ((tid & 63) == 0) outp[t & 1][tid >> 6] = ov;

            __syncthreads();

            if (tid == 0) {
                float o = bo_l;
#pragma unroll
                for (int w = 0; w < 16; ++w) o += outp[t & 1][w];
                out[(size_t)b * Tt + t] = o;
            }
        }
    }

    // final h, c (f32 from registers; one lane per unit)
    if (s == 0) {
        out[(size_t)Bb * Tt + (size_t)b * Hh + u] = h_last;
        out[(size_t)Bb * Tt + (size_t)Bb * Hh + (size_t)b * Hh + u] = c_reg;
    }
}

extern "C" void kernel_launch(void* const* d_in, const int* in_sizes, int n_in,
                              void* d_out, int out_size, void* d_ws, size_t ws_size,
                              hipStream_t stream) {
    (void)in_sizes; (void)n_in; (void)out_size;
    const float* x     = (const float*)d_in[0];
    const float* W_ih  = (const float*)d_in[1];
    const float* b_ih  = (const float*)d_in[2];
    const float* W_hh  = (const float*)d_in[3];
    const float* b_hh  = (const float*)d_in[4];
    const float* W_out = (const float*)d_in[5];
    const float* b_out = (const float*)d_in[6];
    float* out = (float*)d_out;

    uint32_t* anomw = (ws_size >= 512) ? (uint32_t*)d_ws
                                       : (uint32_t*)(out + (size_t)Bb * Tt);

    anom_kernel<<<64, 256, 0, stream>>>(x, anomw);
    lstm_kernel<<<Bb, 1024, 0, stream>>>(x, W_ih, b_ih, W_hh, b_hh, W_out, b_out,
                                         anomw, out);
}

// Round 8
// 8887.743 us; speedup vs baseline: 1.4964x; 1.4964x over previous
//
#include <hip/hip_runtime.h>
#include <hip/hip_fp16.h>

// AlternatingForecastModel: 4096-step LSTM (B=256,H=256) with anomaly memory blend.
// v8 = v5 (proven) + amdgpu_waves_per_eu(2,2) to unlock 256 VGPRs at 512 thr.
//   Allocator evidence r1-r7: VGPR cap = 65536/threads (2-blocks/CU heuristic);
//   launch_bounds 2nd arg (a MIN) never raised it. waves_per_eu(2,2) pins the MAX
//   waves/EU -> budget 512/2 = 256 regs, keeping 2 waves/SIMD latency hiding.
//   Register diet vs v5 (demand ~240 < 256): bias/W_out/b_out in LDS (v7-proven),
//   W=10 ring packed f16 + packed softmax table (v7-proven, absmax 0.0039).
//   All compute/layout primitives identical to v5.

#define Bb 256
#define Tt 4096
#define Ff 16
#define Hh 256
#define PV 23                    // W_hh pairs/row in VGPRs (pairs 0..22)
#define NSL 9                    // W_hh pairs/row in LDS  (pairs 23..31)
#define MEM_DECAY 0.3f
#define SMOOTH 0.1f

typedef _Float16 h2v __attribute__((ext_vector_type(2)));

__device__ __forceinline__ uint32_t pkh2(float a, float b) {
    __half2 h = __floats2half2_rn(a, b);
    return __builtin_bit_cast(uint32_t, h);
}

__device__ __forceinline__ float dot2f(uint32_t a, uint32_t b, float c) {
#if __has_builtin(__builtin_amdgcn_fdot2)
    return __builtin_amdgcn_fdot2(__builtin_bit_cast(h2v, a),
                                  __builtin_bit_cast(h2v, b), c, false);
#else
    h2v x = __builtin_bit_cast(h2v, a), y = __builtin_bit_cast(h2v, b);
    return c + (float)x[0] * (float)y[0] + (float)x[1] * (float)y[1];
#endif
}

__device__ __forceinline__ float sigm_(float x) { return 1.0f / (1.0f + __expf(-x)); }
__device__ __forceinline__ float tanh_(float x) { return 1.0f - 2.0f / (__expf(2.0f * x) + 1.0f); }

// ---------------- pre-kernel: packed anomaly bits (128 u32 words) ----------------
__global__ void __launch_bounds__(256) anom_kernel(const float* __restrict__ x,
                                                   uint32_t* __restrict__ anomw) {
    __shared__ uint32_t part[4][64];
    const int k = blockIdx.x, j = threadIdx.x;
    const int tsub = j & 63, bg = j >> 6;
    const int t = k * 64 + tsub;
    uint32_t a = 0;
    for (int b = bg * 64; b < bg * 64 + 64; ++b)
        a |= (x[((size_t)b * Tt + t) * Ff + (Ff - 1)] != 0.0f) ? 1u : 0u;
    part[bg][tsub] = a;
    __syncthreads();
    if (j < 64) {
        uint32_t any = part[0][j] | part[1][j] | part[2][j] | part[3][j];
        unsigned long long m = __ballot(any != 0);
        if (j == 0) {
            anomw[2 * k]     = (uint32_t)(m & 0xffffffffull);
            anomw[2 * k + 1] = (uint32_t)(m >> 32);
        }
    }
}

// ---------------- main kernel ----------------
__global__ void __launch_bounds__(512, 2)
__attribute__((amdgpu_waves_per_eu(2, 2)))
lstm_kernel(
    const float* __restrict__ x,
    const float* __restrict__ W_ih, const float* __restrict__ b_ih,
    const float* __restrict__ W_hh, const float* __restrict__ b_hh,
    const float* __restrict__ W_out, const float* __restrict__ b_out,
    const uint32_t* __restrict__ anomw,
    float* __restrict__ out)
{
    __shared__ uint4    lds_w4[2 * NSL * 512];        // 147456 B
    __shared__ float    bias_l[1024];                 // 4096 B  bias[u*4+G]
    __shared__ float    wout_l[256];                  // 1024 B
    __shared__ uint32_t xst[64 * 8];                  // 2048 B
    __shared__ uint32_t hbuf[2 * 144];                // 1152 B (h f16 pairs, stride 36/slice)
    __shared__ uint32_t abits[128];                   // 512 B
    __shared__ uint32_t w2h[64];                      // packed f16 softmax table
    __shared__ float    outp[2][8];
    __shared__ float    bo_l;

    const int tid = threadIdx.x;          // 0..511
    const int b   = blockIdx.x;
    const int s   = tid & 3;              // k-slice
    const int g   = tid >> 2;             // 0..127 -> units {2g, 2g+1}
    const int u0  = 2 * g;
    const int myu = u0 + (s & 1);         // own unit (lanes s and s+2 duplicate)

    // ---- VGPR W_hh: wv[r][k], r = u01*4+G, row = G*256 + u0 + u01, cols 64s+2k..+1
    uint32_t wv[8][PV];
#pragma unroll
    for (int r = 0; r < 8; ++r) {
        const int row = ((r & 3) << 8) + u0 + (r >> 2);
        const float* src = W_hh + (size_t)row * Hh + 64 * s;
#pragma unroll
        for (int k = 0; k < PV; ++k) {
            const float2 w2v = *reinterpret_cast<const float2*>(src + 2 * k);
            wv[r][k] = pkh2(w2v.x, w2v.y);
        }
    }
    // ---- VGPR W_ih: slice s owns features 4s..4s+3 (2 pairs)
    uint32_t wx[8][2];
#pragma unroll
    for (int r = 0; r < 8; ++r) {
        const int row = ((r & 3) << 8) + u0 + (r >> 2);
        const float* src = W_ih + (size_t)row * (Ff + 1) + 4 * s;
        wx[r][0] = pkh2(src[0], src[1]);
        wx[r][1] = pkh2(src[2], src[3]);
    }

    // ---- LDS W_hh pairs PV..PV+NSL-1: chunk c = j*2+u01, [c][tid][4dw]
#pragma unroll 1
    for (int c = 0; c < 2 * NSL; ++c) {
        const int j = c >> 1, u01 = c & 1;
        const int col = 64 * s + 2 * (PV + j);
        uint32_t d[4];
#pragma unroll
        for (int G = 0; G < 4; ++G) {
            const int row = (G << 8) + u0 + u01;
            const float2 w2v = *reinterpret_cast<const float2*>(
                W_hh + (size_t)row * Hh + col);
            d[G] = pkh2(w2v.x, w2v.y);
        }
        lds_w4[c * 512 + tid] = make_uint4(d[0], d[1], d[2], d[3]);
    }

    // ---- misc LDS init
    for (int i = tid; i < 1024; i += 512)
        bias_l[i] = b_ih[((i & 3) << 8) + (i >> 2)] + b_hh[((i & 3) << 8) + (i >> 2)];
    if (tid < 256) wout_l[tid] = W_out[tid];
    if (tid == 0) bo_l = b_out[0];
    if (tid < 128) abits[tid] = anomw[tid];
    if (tid < 288) hbuf[tid] = 0u;                    // h0 = 0 (both phases)
    if (tid < 50) {
        const int cc = tid / 5 + 1, j = tid % 5;
        float S = 0.f;
        for (int i = 0; i < cc; ++i) S += __expf((float)i);
        const int shift = 10 - cc;
        const int p0 = 2 * j, p1 = 2 * j + 1;
        const float v0 = (p0 >= shift) ? __expf((float)(p0 - shift)) / S : 0.f;
        const float v1 = (p1 >= shift) ? __expf((float)(p1 - shift)) / S : 0.f;
        w2h[cc * 5 + j] = pkh2(v0, v1);
    }

    float c_reg = 0.f, h_last = 0.f;
    uint32_t bufp[5];                     // W=10 ring, packed f16, oldest = low of bufp[0]
#pragma unroll
    for (int i = 0; i < 5; ++i) bufp[i] = 0u;
    int count = 1;

    __syncthreads();

    unsigned short* hs = reinterpret_cast<unsigned short*>(hbuf);

#pragma unroll 1
    for (int tc = 0; tc < Tt / 64; ++tc) {
        {   // stage 64 steps of x as f16 pairs (1 float2 per thread)
            const int ts = tc * 64 + (tid >> 3), q = tid & 7;
            const float2 xv = *reinterpret_cast<const float2*>(
                &x[((size_t)b * Tt + ts) * Ff + 2 * q]);
            xst[(tid >> 3) * 8 + q] = pkh2(xv.x, xv.y);
        }
        __syncthreads();

#pragma unroll 1
        for (int tt = 0; tt < 64; ++tt) {
            const int t = tc * 64 + tt;
            const uint32_t* hb = hbuf + (t & 1) * 144 + s * 36;

            float acc[8];
#pragma unroll
            for (int r = 0; r < 8; ++r) acc[r] = 0.f;

            // ---- phase A: h pairs 23..31 + LDS-resident weight MACs
            {
                const uint32_t hA0 = hb[23];
                const uint4 hA1 = *reinterpret_cast<const uint4*>(hb + 24);
                const uint4 hA2 = *reinterpret_cast<const uint4*>(hb + 28);
                const uint32_t hkA[9] = {hA0, hA1.x, hA1.y, hA1.z, hA1.w,
                                              hA2.x, hA2.y, hA2.z, hA2.w};
#pragma unroll
                for (int j = 0; j < NSL; ++j) {
                    const uint32_t hk = hkA[j];
#pragma unroll
                    for (int u01 = 0; u01 < 2; ++u01) {
                        const uint4 wc = lds_w4[(j * 2 + u01) * 512 + tid];
                        acc[u01 * 4 + 0] = dot2f(wc.x, hk, acc[u01 * 4 + 0]);
                        acc[u01 * 4 + 1] = dot2f(wc.y, hk, acc[u01 * 4 + 1]);
                        acc[u01 * 4 + 2] = dot2f(wc.z, hk, acc[u01 * 4 + 2]);
                        acc[u01 * 4 + 3] = dot2f(wc.w, hk, acc[u01 * 4 + 3]);
                    }
                }
            }
            // ---- x part
            {
                const uint32_t xp0 = xst[tt * 8 + 2 * s];
                const uint32_t xp1 = xst[tt * 8 + 2 * s + 1];
#pragma unroll
                for (int r = 0; r < 8; ++r) {
                    acc[r] = dot2f(wx[r][0], xp0, acc[r]);
                    acc[r] = dot2f(wx[r][1], xp1, acc[r]);
                }
            }
            __builtin_amdgcn_sched_barrier(0);
            // ---- phase B1: h pairs 0..11 + VGPR weight MACs
            {
                const uint4 h0 = *reinterpret_cast<const uint4*>(hb + 0);
                const uint4 h1 = *reinterpret_cast<const uint4*>(hb + 4);
                const uint4 h2 = *reinterpret_cast<const uint4*>(hb + 8);
                const uint32_t hkB[12] = {h0.x, h0.y, h0.z, h0.w,
                                          h1.x, h1.y, h1.z, h1.w,
                                          h2.x, h2.y, h2.z, h2.w};
#pragma unroll
                for (int k = 0; k < 12; ++k) {
                    const uint32_t hk = hkB[k];
#pragma unroll
                    for (int r = 0; r < 8; ++r)
                        acc[r] = dot2f(wv[r][k], hk, acc[r]);
                }
            }
            __builtin_amdgcn_sched_barrier(0);
            // ---- phase B2: h pairs 12..22 + VGPR weight MACs
            {
                const uint4 h3 = *reinterpret_cast<const uint4*>(hb + 12);
                const uint4 h4 = *reinterpret_cast<const uint4*>(hb + 16);
                const uint32_t h20 = hb[20], h21 = hb[21], h22 = hb[22];
                const uint32_t hkC[11] = {h3.x, h3.y, h3.z, h3.w,
                                          h4.x, h4.y, h4.z, h4.w,
                                          h20, h21, h22};
#pragma unroll
                for (int k = 0; k < 11; ++k) {
                    const uint32_t hk = hkC[k];
#pragma unroll
                    for (int r = 0; r < 8; ++r)
                        acc[r] = dot2f(wv[r][12 + k], hk, acc[r]);
                }
            }

            // butterfly across the 4 k-slices
#pragma unroll
            for (int r = 0; r < 8; ++r) acc[r] += __shfl_xor(acc[r], 1, 64);
#pragma unroll
            for (int r = 0; r < 8; ++r) acc[r] += __shfl_xor(acc[r], 2, 64);

            // bias from LDS (b128 broadcast, once per step)
            const float4 bi = *reinterpret_cast<const float4*>(&bias_l[myu * 4]);
            const float g0 = ((s & 1) ? acc[4] : acc[0]) + bi.x;
            const float g1 = ((s & 1) ? acc[5] : acc[1]) + bi.y;
            const float g2 = ((s & 1) ? acc[6] : acc[2]) + bi.z;
            const float g3 = ((s & 1) ? acc[7] : acc[3]) + bi.w;

            const float ig = sigm_(g0);
            const float fg = sigm_(g1);
            const float gg = tanh_(g2);
            const float og = sigm_(g3);
            const float new_c = fg * c_reg + ig * gg;
            const float new_h = og * tanh_(new_c);

            const uint32_t an = (abits[t >> 5] >> (t & 31)) & 1u;
            if (an) {
                const uint32_t* wt = w2h + count * 5;   // uniform addr -> broadcast
                float wsum = 0.f;
#pragma unroll
                for (int j = 0; j < 5; ++j) wsum = dot2f(wt[j], bufp[j], wsum);
                const float blend = wsum * (1.0f - MEM_DECAY) + new_c * MEM_DECAY;
                c_reg = c_reg * (1.0f - SMOOTH) + blend * SMOOTH;
            } else {
                c_reg = new_c;
                __half nch = __float2half_rn(new_c);
                const uint32_t nc = (uint32_t)__builtin_bit_cast(unsigned short, nch);
                bufp[0] = __builtin_amdgcn_alignbit(bufp[1], bufp[0], 16);
                bufp[1] = __builtin_amdgcn_alignbit(bufp[2], bufp[1], 16);
                bufp[2] = __builtin_amdgcn_alignbit(bufp[3], bufp[2], 16);
                bufp[3] = __builtin_amdgcn_alignbit(bufp[4], bufp[3], 16);
                bufp[4] = __builtin_amdgcn_alignbit(nc,      bufp[4], 16);
                count = min(count + 1, 10);
            }
            h_last = new_h;

            // publish h (f16) for step t+1, padded layout
            if (s < 2) {
                __half hv = __float2half_rn(new_h);
                hs[((t + 1) & 1) * 288 + (myu >> 6) * 72 + (myu & 63)] =
                    __builtin_bit_cast(unsigned short, hv);
            }
            // out[b][t]: per-wave shfl reduce (units counted once via s<2 mask)
            float ov = (s < 2) ? new_h * wout_l[myu] : 0.f;
#pragma unroll
            for (int m = 1; m < 64; m <<= 1) ov += __shfl_xor(ov, m, 64);
            if ((tid & 63) == 0) outp[t & 1][tid >> 6] = ov;

            __syncthreads();

            if (tid == 0) {
                float o = bo_l;
#pragma unroll
                for (int w = 0; w < 8; ++w) o += outp[t & 1][w];
                out[(size_t)b * Tt + t] = o;
            }
        }
    }

    // final h, c (f32 from registers)
    if (s < 2) {
        out[(size_t)Bb * Tt + (size_t)b * Hh + myu] = h_last;
        out[(size_t)Bb * Tt + (size_t)Bb * Hh + (size_t)b * Hh + myu] = c_reg;
    }
}

extern "C" void kernel_launch(void* const* d_in, const int* in_sizes, int n_in,
                              void* d_out, int out_size, void* d_ws, size_t ws_size,
                              hipStream_t stream) {
    (void)in_sizes; (void)n_in; (void)out_size;
    const float* x     = (const float*)d_in[0];
    const float* W_ih  = (const float*)d_in[1];
    const float* b_ih  = (const float*)d_in[2];
    const float* W_hh  = (const float*)d_in[3];
    const float* b_hh  = (const float*)d_in[4];
    const float* W_out = (const float*)d_in[5];
    const float* b_out = (const float*)d_in[6];
    float* out = (float*)d_out;

    uint32_t* anomw = (ws_size >= 512) ? (uint32_t*)d_ws
                                       : (uint32_t*)(out + (size_t)Bb * Tt);

    anom_kernel<<<64, 256, 0, stream>>>(x, anomw);
    lstm_kernel<<<Bb, 512, 0, stream>>>(x, W_ih, b_ih, W_hh, b_hh, W_out, b_out,
                                        anomw, out);
}